// Round 1
// baseline (140.882 us; speedup 1.0000x reference)
//
#include <hip/hip_runtime.h>

// TVConv: per-pixel spatially-varying 3x3 depthwise conv.
// x: (8,96,128,128) fp32, wm: (1,96,3,3,128,128) fp32, out: (8,96,128,128).
//
// R6 theory: the LDS-staged version (51.9us) was latency/structure-bound,
// not byte-bound: VALUBusy 9.4%, HBM 2.1 TB/s, occupancy 25%, nothing
// saturated. Its load-all -> __syncthreads (vmcnt(0) drain) -> compute-all
// phases + 41KB LDS (3 blk/CU, 2 sequential rounds) serialized the machine.
// This version streams: wt once device-wide in registers (kept from R5),
// x read directly per batch (3 float4 rows, vertical reuse served by L1/L2
// since neighbor rows live in the same block), shfl for the horizontal halo.
// No LDS, no barrier, whole grid resident (~6 waves/SIMD at ~80 VGPR).
// Boundary rows: zero wt rows once (0 * finite = 0), row offset clamped so
// no OOB; boundary cols: shfl cross-row pulls masked at lanes w4==0/31.

namespace {
constexpr int B = 8, C = 96, H = 128, W = 128;
constexpr int HW = H * W;
}

__global__ __launch_bounds__(256, 6) void tvconv_kernel(
    const float* __restrict__ x,
    const float* __restrict__ wm,
    float* __restrict__ out) {
  const int t  = threadIdx.x;
  const int c  = blockIdx.x >> 4;          // 16 h-octets per channel
  const int h0 = (blockIdx.x & 15) * 8;
  const int lr = t >> 5;                   // local row 0..7
  const int w4 = t & 31;
  const int h  = h0 + lr;
  const int w  = w4 * 4;

  const float4 zero4 = make_float4(0.f, 0.f, 0.f, 0.f);

  // ---- 9 per-pixel weights into registers (requested ONCE device-wide) ----
  const float* wp = wm + (size_t)c * 9 * HW + h * W + w;
  float4 wt[9];
#pragma unroll
  for (int k = 0; k < 9; ++k) {
    wt[k] = *reinterpret_cast<const float4*>(wp + (size_t)k * HW);
  }

  // Vertical padding: zero the weight taps that face padding, then the
  // (clamped-row) x values they multiply contribute exactly 0.
  if (h == 0)     { wt[0] = zero4; wt[1] = zero4; wt[2] = zero4; }
  if (h == H - 1) { wt[6] = zero4; wt[7] = zero4; wt[8] = zero4; }
  const int up = (h == 0)     ? 0 : W;     // clamped row strides (no OOB)
  const int dn = (h == H - 1) ? 0 : W;

  const bool at_left  = (w4 == 0);
  const bool at_right = (w4 == 31);

  const float* xb = x   + (size_t)c * HW + h * W + w;   // batch 0
  float*       ob = out + (size_t)c * HW + h * W + w;

#pragma unroll
  for (int b = 0; b < B; ++b) {
    const float4 r0 = *reinterpret_cast<const float4*>(xb - up);
    const float4 r1 = *reinterpret_cast<const float4*>(xb);
    const float4 r2 = *reinterpret_cast<const float4*>(xb + dn);
    const float4 rows[3] = {r0, r1, r2};

    float acc[4] = {0.f, 0.f, 0.f, 0.f};
#pragma unroll
    for (int i = 0; i < 3; ++i) {
      const float4 ctr = rows[i];
      float left  = __shfl_up(ctr.w, 1);
      float right = __shfl_down(ctr.x, 1);
      if (at_left)  left  = 0.f;   // lanes 0/32: w==0 (cross-row pull masked)
      if (at_right) right = 0.f;   // lanes 31/63: w+4==W
      const float xv[6] = {left, ctr.x, ctr.y, ctr.z, ctr.w, right};
#pragma unroll
      for (int j = 0; j < 3; ++j) {
        const float4 wv = wt[i * 3 + j];
        const float wa[4] = {wv.x, wv.y, wv.z, wv.w};
#pragma unroll
        for (int m = 0; m < 4; ++m) {
          acc[m] += wa[m] * xv[m + j];  // pixel w+m, tap j reads x[w+m+j-1]
        }
      }
    }
    float4 o;
    o.x = acc[0]; o.y = acc[1]; o.z = acc[2]; o.w = acc[3];
    *reinterpret_cast<float4*>(ob) = o;

    xb += (size_t)C * HW;
    ob += (size_t)C * HW;
  }
}

extern "C" void kernel_launch(void* const* d_in, const int* in_sizes, int n_in,
                              void* d_out, int out_size, void* d_ws, size_t ws_size,
                              hipStream_t stream) {
  const float* x  = (const float*)d_in[0];
  const float* wm = (const float*)d_in[1];
  float* out = (float*)d_out;

  const int blocks = C * (H / 8);  // 1536
  tvconv_kernel<<<blocks, 256, 0, stream>>>(x, wm, out);
}

// Round 3
// 139.462 us; speedup vs baseline: 1.0102x; 1.0102x over previous
//
#include <hip/hip_runtime.h>

// TVConv: per-pixel spatially-varying 3x3 depthwise conv.
// x: (8,96,128,128) fp32, wm: (1,96,3,3,128,128) fp32, out: (8,96,128,128).
//
// R7b: same as R7 (compile fix: nontemporal builtins need a native clang
// ext_vector type, not HIP_vector_type float4).
// Over R6 (44.6us, 5.8 TB/s request rate, VGPR=40, latency-limited serial
// per-batch loads):
//  1. Row-pair sharing via __shfl_xor(.,32): each wave holds rows
//     (h0+2k, h0+2k+1) in its two halves. The partner half's center row
//     IS my missing vertical neighbor, so each thread loads only 2 rows
//     (center + outer) instead of 3. x requests 151->101 MB; total
//     requested 208 MB (wt 56.6 once device-wide + x 101 + out 50).
//  2. Software pipeline depth 2: batch b+1's two row-loads issue before
//     batch b's compute, so VMEM latency hides under FMAs.
// wt loads / out stores are nontemporal (single-use; don't evict x).
// Vertical padding: zero wt rows once (0 * finite = 0), row offsets
// clamped so no OOB. Horizontal halo via shfl_up/down, masked at
// w4==0/31 which coincide with W-padding (also masks the lane31<->32
// row-crossing pulls positionally).

namespace {
constexpr int B = 8, C = 96, H = 128, W = 128;
constexpr int HW = H * W;
}

typedef float f4 __attribute__((ext_vector_type(4)));

__global__ __launch_bounds__(256, 6) void tvconv_kernel(
    const float* __restrict__ x,
    const float* __restrict__ wm,
    float* __restrict__ out) {
  const int t  = threadIdx.x;
  const int c  = blockIdx.x >> 4;          // 16 h-octets per channel
  const int h0 = (blockIdx.x & 15) * 8;
  const int lr = t >> 5;                   // local row 0..7
  const int w4 = t & 31;
  const int h  = h0 + lr;
  const int w  = w4 * 4;

  // ---- 9 per-pixel weights into registers (requested ONCE device-wide) ----
  const float* wp = wm + (size_t)c * 9 * HW + h * W + w;
  f4 wt[9];
#pragma unroll
  for (int k = 0; k < 9; ++k) {
    wt[k] = __builtin_nontemporal_load(
        reinterpret_cast<const f4*>(wp + (size_t)k * HW));
  }

  // Vertical padding: zero the wt taps that face padding; the clamped x
  // rows they multiply then contribute exactly 0.
  if (h == 0)     { wt[0] = 0.f; wt[1] = 0.f; wt[2] = 0.f; }
  if (h == H - 1) { wt[6] = 0.f; wt[7] = 0.f; wt[8] = 0.f; }
  const int up = (h == 0)     ? 0 : W;     // clamped row strides (no OOB)
  const int dn = (h == H - 1) ? 0 : W;

  // Row-pair sharing: within a wave, lanes 0-31 hold row h0+2k, lanes
  // 32-63 hold row h0+2k+1. Lower half loads its UP row as "outer";
  // upper half loads its DOWN row. The remaining vertical neighbor comes
  // from the partner half via shfl_xor 32.
  const bool lower = ((lr & 1) == 0);
  const int ooff = lower ? -up : dn;

  const bool at_left  = (w4 == 0);
  const bool at_right = (w4 == 31);

  const float* xb = x   + (size_t)c * HW + h * W + w;   // batch 0
  float*       ob = out + (size_t)c * HW + h * W + w;

  // Prime the pipeline: batch 0 loads in flight.
  f4 nctr = *reinterpret_cast<const f4*>(xb);
  f4 noth = *reinterpret_cast<const f4*>(xb + ooff);

#pragma unroll
  for (int b = 0; b < B; ++b) {
    const f4 cc = nctr;
    const f4 oo = noth;
    if (b + 1 < B) {                        // prefetch batch b+1
      xb += (size_t)C * HW;
      nctr = *reinterpret_cast<const f4*>(xb);
      noth = *reinterpret_cast<const f4*>(xb + ooff);
    }

    // Exchange center rows between the wave halves.
    f4 prt;
    prt.x = __shfl_xor(cc.x, 32);
    prt.y = __shfl_xor(cc.y, 32);
    prt.z = __shfl_xor(cc.z, 32);
    prt.w = __shfl_xor(cc.w, 32);

    const f4 r0 = lower ? oo  : prt;        // row h-1
    const f4 r1 = cc;                       // row h
    const f4 r2 = lower ? prt : oo;         // row h+1
    const f4 rows[3] = {r0, r1, r2};

    float acc[4] = {0.f, 0.f, 0.f, 0.f};
#pragma unroll
    for (int i = 0; i < 3; ++i) {
      const f4 ctr = rows[i];
      float left  = __shfl_up(ctr.w, 1);
      float right = __shfl_down(ctr.x, 1);
      if (at_left)  left  = 0.f;   // lanes 0/32: w==0 (cross-row pull masked)
      if (at_right) right = 0.f;   // lanes 31/63: w+4==W
      const float xv[6] = {left, ctr.x, ctr.y, ctr.z, ctr.w, right};
#pragma unroll
      for (int j = 0; j < 3; ++j) {
        const f4 wv = wt[i * 3 + j];
        const float wa[4] = {wv.x, wv.y, wv.z, wv.w};
#pragma unroll
        for (int m = 0; m < 4; ++m) {
          acc[m] += wa[m] * xv[m + j];  // pixel w+m, tap j reads x[w+m+j-1]
        }
      }
    }
    f4 o;
    o.x = acc[0]; o.y = acc[1]; o.z = acc[2]; o.w = acc[3];
    __builtin_nontemporal_store(o, reinterpret_cast<f4*>(ob));
    ob += (size_t)C * HW;
  }
}

extern "C" void kernel_launch(void* const* d_in, const int* in_sizes, int n_in,
                              void* d_out, int out_size, void* d_ws, size_t ws_size,
                              hipStream_t stream) {
  const float* x  = (const float*)d_in[0];
  const float* wm = (const float*)d_in[1];
  float* out = (float*)d_out;

  const int blocks = C * (H / 8);  // 1536
  tvconv_kernel<<<blocks, 256, 0, stream>>>(x, wm, out);
}

// Round 5
// 138.155 us; speedup vs baseline: 1.0197x; 1.0095x over previous
//
#include <hip/hip_runtime.h>

// TVConv: per-pixel spatially-varying 3x3 depthwise conv.
// x: (8,96,128,128) fp32, wm: (1,96,3,3,128,128) fp32, out: (8,96,128,128).
//
// R8 (retry; previous submission hit an infra failure, not a kernel error).
// Vertical register blocking R=2 over R7b (~<40us, 208 MB requested).
// Each thread computes output rows h,h+1. A wave covers 6 x-rows; each
// thread loads 3 (Lf/Lm/Ln), the half-waves exchange one boundary row via
// shfl_xor(.,32). x requests drop 2.0x -> 1.5x of footprint; total
// requested 182 MB (wt 56.6 once device-wide + x 75.5 + out 50).
//
// Half-wave asymmetry is folded into one-time prologue address math so the
// batch loop is divergence-free:
//  - upper half loads wt with tap-row order FLIPPED (k -> 6-3*(k/3)+k%3)
//    and x offsets mirrored; then both halves run identical accumulation
//    (accP pairs seq1=(Lf,Lm,Ln), accQ pairs seq2=(Lm,Ln,P)).
//  - vertical pad collapses to: hP in {0,H-1} -> zero wtP[0..2]
//    (top-pad unflipped and bottom-pad flipped hit the same regs);
//    clamped row offsets keep loads in-bounds (0 * finite = 0).
// Horizontal halo via shfl_up/down masked at w4==0/31 (coincides with
// W-padding, also masks lane 31<->32 row-crossing pulls).
// Software pipeline depth 2 (batch b+1 rows in flight during compute b).
// VGPR ~140 -> launch_bounds(256,3); 768 blocks = 12 waves/CU, one round.

namespace {
constexpr int B = 8, C = 96, H = 128, W = 128;
constexpr int HW = H * W;
}

typedef float f4 __attribute__((ext_vector_type(4)));

__global__ __launch_bounds__(256, 3) void tvconv_kernel(
    const float* __restrict__ x,
    const float* __restrict__ wm,
    float* __restrict__ out) {
  const int t  = threadIdx.x;
  const int c  = blockIdx.x >> 3;          // 8 row-groups of 16 per channel
  const int h0 = (blockIdx.x & 7) * 16;
  const int tr = t >> 5;                   // thread-row 0..7
  const int w4 = t & 31;
  const int w  = w4 * 4;
  const int h  = h0 + tr * 2;              // this thread's output rows h, h+1
  const bool lower = ((tr & 1) == 0);      // lower/upper half of the wave

  const int hP = lower ? h : h + 1;        // output row paired with seq1
  const int hQ = lower ? h + 1 : h;        // output row paired with seq2

  // ---- wt into registers (requested ONCE device-wide); upper half loads
  // with tap-row order flipped so the batch loop is uniform. ----
  f4 wtP[9], wtQ[9];
  {
    const float* wc = wm + (size_t)c * 9 * HW + w;
#pragma unroll
    for (int k = 0; k < 9; ++k) {
      const int ti = k / 3, tj = k % 3;
      const int kk = lower ? k : (6 - 3 * ti + tj);   // tap-row flip
      wtP[k] = __builtin_nontemporal_load(
          reinterpret_cast<const f4*>(wc + (size_t)kk * HW + hP * W));
      wtQ[k] = __builtin_nontemporal_load(
          reinterpret_cast<const f4*>(wc + (size_t)kk * HW + hQ * W));
    }
  }
  // Vertical padding: row 0's up-taps (unflipped) and row 127's down-taps
  // (flipped) both live in wtP[0..2]. hQ is never a boundary row.
  if (hP == 0 || hP == H - 1) { wtP[0] = 0.f; wtP[1] = 0.f; wtP[2] = 0.f; }

  // ---- x row offsets from row-h base; mirrored for upper; clamped. ----
  // lower: Lf=h-1, Lm=h, Ln=h+1   | upper: Lf=h+2, Lm=h+1, Ln=h
  const int offF = lower ? ((h == 0) ? 0 : -W)
                         : ((h == H - 2) ? W : 2 * W);
  const int offM = lower ? 0 : W;
  const int offN = lower ? W : 0;

  const bool at_left  = (w4 == 0);
  const bool at_right = (w4 == 31);

  const float* xb = x + (size_t)c * HW + h * W + w;
  float* obP = out + (size_t)c * HW + hP * W + w;
  float* obQ = out + (size_t)c * HW + hQ * W + w;

  // Prime the pipeline: batch 0 rows in flight.
  f4 nF = *reinterpret_cast<const f4*>(xb + offF);
  f4 nM = *reinterpret_cast<const f4*>(xb + offM);
  f4 nN = *reinterpret_cast<const f4*>(xb + offN);

  // Build the 6-wide horizontal window for one row.
  auto make_xv = [&](float* xv, const f4 r) {
    float left  = __shfl_up(r.w, 1);
    float right = __shfl_down(r.x, 1);
    if (at_left)  left  = 0.f;
    if (at_right) right = 0.f;
    xv[0] = left; xv[1] = r.x; xv[2] = r.y; xv[3] = r.z; xv[4] = r.w;
    xv[5] = right;
  };
  // acc += wt tap-row i applied to window xv.
  auto acc_row = [&](float* acc, const f4* wt, const int i, const float* xv) {
#pragma unroll
    for (int j = 0; j < 3; ++j) {
      const f4 wv = wt[i * 3 + j];
      const float wa[4] = {wv.x, wv.y, wv.z, wv.w};
#pragma unroll
      for (int m = 0; m < 4; ++m) acc[m] += wa[m] * xv[m + j];
    }
  };

#pragma unroll
  for (int b = 0; b < B; ++b) {
    const f4 Lf = nF, Lm = nM, Ln = nN;
    if (b + 1 < B) {                        // prefetch batch b+1
      xb += (size_t)C * HW;
      nF = *reinterpret_cast<const f4*>(xb + offF);
      nM = *reinterpret_cast<const f4*>(xb + offM);
      nN = *reinterpret_cast<const f4*>(xb + offN);
    }

    // Exchange the near-edge row between the wave halves:
    // lower sends h+1, receives h+2; upper sends h, receives h-1.
    f4 P;
    P.x = __shfl_xor(Ln.x, 32);
    P.y = __shfl_xor(Ln.y, 32);
    P.z = __shfl_xor(Ln.z, 32);
    P.w = __shfl_xor(Ln.w, 32);

    float xvF[6], xvM[6], xvN[6], xvP[6];
    make_xv(xvF, Lf);
    make_xv(xvM, Lm);
    make_xv(xvN, Ln);
    make_xv(xvP, P);

    float accP[4] = {0.f, 0.f, 0.f, 0.f};
    float accQ[4] = {0.f, 0.f, 0.f, 0.f};
    acc_row(accP, wtP, 0, xvF);             // seq1 = (Lf, Lm, Ln)
    acc_row(accP, wtP, 1, xvM);
    acc_row(accP, wtP, 2, xvN);
    acc_row(accQ, wtQ, 0, xvM);             // seq2 = (Lm, Ln, P)
    acc_row(accQ, wtQ, 1, xvN);
    acc_row(accQ, wtQ, 2, xvP);

    f4 oP, oQ;
    oP.x = accP[0]; oP.y = accP[1]; oP.z = accP[2]; oP.w = accP[3];
    oQ.x = accQ[0]; oQ.y = accQ[1]; oQ.z = accQ[2]; oQ.w = accQ[3];
    __builtin_nontemporal_store(oP, reinterpret_cast<f4*>(obP));
    __builtin_nontemporal_store(oQ, reinterpret_cast<f4*>(obQ));
    obP += (size_t)C * HW;
    obQ += (size_t)C * HW;
  }
}

extern "C" void kernel_launch(void* const* d_in, const int* in_sizes, int n_in,
                              void* d_out, int out_size, void* d_ws, size_t ws_size,
                              hipStream_t stream) {
  const float* x  = (const float*)d_in[0];
  const float* wm = (const float*)d_in[1];
  float* out = (float*)d_out;

  const int blocks = C * (H / 16);  // 768
  tvconv_kernel<<<blocks, 256, 0, stream>>>(x, wm, out);
}

// Round 6
// 138.035 us; speedup vs baseline: 1.0206x; 1.0009x over previous
//
#include <hip/hip_runtime.h>

// TVConv: per-pixel spatially-varying 3x3 depthwise conv.
// x: (8,96,128,128) fp32, wm: (1,96,3,3,128,128) fp32, out: (8,96,128,128).
//
// R9: cross-wave vertical sharing via a small LDS row-exchange, over R8
// (est ~31us, 182 MB requested: wt 56.6 + x 75.5 (1.5x) + out 50.3).
// Each thread computes rows r0=h0+2tr, r1=r0+1 and loads ONLY those two
// rows from global (register round-trip). It ds_writes them into a
// per-block [2][18][128] f32 slab and ds_reads its outer neighbors
// (r0-1, r1+1) written by adjacent threads. Only tr==0 / tr==7 load one
// extra block-halo row. x amplification 1.5x -> 18/16 = 1.125x; total
// requested 163.5 MB (floor 157).
//
// This is NOT the R1-R5 LDS structure that lost to streaming (51.9us):
// that one pushed ALL x through a monolithic global_load_lds slab with a
// full vmcnt(0) drain at one barrier, 41 KB -> 3 blk/CU, 2 grid rounds.
// Here LDS carries only the row exchange; loads are 2-3 f4/thread issued
// before compute (latency hidden under ~100 VALU ops), double-buffered
// over batches with ONE barrier per batch:
//   compute b reads xs[b&1]; batch b+1 written to xs[(b+1)&1]; barrier.
//   Reads of buf A (iter b) vs overwrite of A (iter b+2... wait: iter b+1
//   writes A) are separated by iter b's barrier; __syncthreads drains each
//   wave's own lgkm before entry, so read-before-overwrite holds.
// Geometry is uniform (no R8 half-wave mirror / tap-flip needed).
// Vertical pad: r0==0 -> zero wtP[0..2]; r1==H-1 -> zero wtQ[6..8]; halo
// row addresses clamped (their content is multiplied by the zeroed taps).
// Horizontal halo via shfl_up/down masked at w4==0/31 (coincides with
// W-padding; also masks lane 31<->32 cross-row pulls).

namespace {
constexpr int B = 8, C = 96, H = 128, W = 128;
constexpr int HW = H * W;
constexpr int ROWS = 16;   // output rows per block
constexpr int SLOTS = 18;  // staged x rows incl. 2 halo
}

typedef float f4 __attribute__((ext_vector_type(4)));

__global__ __launch_bounds__(256, 3) void tvconv_kernel(
    const float* __restrict__ x,
    const float* __restrict__ wm,
    float* __restrict__ out) {
  __shared__ __align__(16) float xs[2][SLOTS][W];   // 18432 B

  const int t  = threadIdx.x;
  const int c  = blockIdx.x >> 3;          // 8 row-groups of 16 per channel
  const int h0 = (blockIdx.x & 7) * ROWS;
  const int tr = t >> 5;                   // thread-row 0..7
  const int w4 = t & 31;
  const int w  = w4 * 4;
  const int r0 = h0 + 2 * tr;              // this thread's output rows
  const int r1 = r0 + 1;

  // ---- 18 wt vectors into registers (requested ONCE device-wide) ----
  const float* wc = wm + (size_t)c * 9 * HW + w;
  f4 wtP[9], wtQ[9];
#pragma unroll
  for (int k = 0; k < 9; ++k) {
    wtP[k] = __builtin_nontemporal_load(
        reinterpret_cast<const f4*>(wc + (size_t)k * HW + r0 * W));
    wtQ[k] = __builtin_nontemporal_load(
        reinterpret_cast<const f4*>(wc + (size_t)k * HW + r1 * W));
  }
  if (r0 == 0)     { wtP[0] = 0.f; wtP[1] = 0.f; wtP[2] = 0.f; }
  if (r1 == H - 1) { wtQ[6] = 0.f; wtQ[7] = 0.f; wtQ[8] = 0.f; }

  // ---- block-halo roles: tr0 loads row h0-1, tr7 loads row h0+16 ----
  const bool up_halo  = (tr == 0);
  const bool dn_halo  = (tr == 7);
  const bool has_halo = up_halo || dn_halo;
  const int halo_row  = up_halo ? max(h0 - 1, 0) : min(h0 + ROWS, H - 1);
  const int halo_slot = up_halo ? 0 : (SLOTS - 1);

  const bool at_left  = (w4 == 0);
  const bool at_right = (w4 == 31);

  const size_t bstride = (size_t)C * HW;
  const float* xb = x + (size_t)c * HW + w;            // batch 0, col w
  float* ob0 = out + (size_t)c * HW + (size_t)r0 * W + w;
  float* ob1 = ob0 + W;

  // Build the 6-wide horizontal window for one row.
  auto make_xv = [&](float* xv, const f4 r) {
    float left  = __shfl_up(r.w, 1);
    float right = __shfl_down(r.x, 1);
    if (at_left)  left  = 0.f;
    if (at_right) right = 0.f;
    xv[0] = left; xv[1] = r.x; xv[2] = r.y; xv[3] = r.z; xv[4] = r.w;
    xv[5] = right;
  };
  // acc += wt tap-row i applied to window xv.
  auto acc_row = [&](float* acc, const f4* wt, const int i, const float* xv) {
#pragma unroll
    for (int j = 0; j < 3; ++j) {
      const f4 wv = wt[i * 3 + j];
      const float wa[4] = {wv.x, wv.y, wv.z, wv.w};
#pragma unroll
      for (int m = 0; m < 4; ++m) acc[m] += wa[m] * xv[m + j];
    }
  };

  // ---- prologue: batch 0 rows -> regs -> LDS buf0 ----
  f4 c0 = *reinterpret_cast<const f4*>(xb + (size_t)r0 * W);
  f4 c1 = *reinterpret_cast<const f4*>(xb + (size_t)r1 * W);
  f4 ch;
  if (has_halo) ch = *reinterpret_cast<const f4*>(xb + (size_t)halo_row * W);
  {
    float* s = &xs[0][0][0];
    *reinterpret_cast<f4*>(s + (2 * tr + 1) * W + w) = c0;
    *reinterpret_cast<f4*>(s + (2 * tr + 2) * W + w) = c1;
    if (has_halo) *reinterpret_cast<f4*>(s + halo_slot * W + w) = ch;
  }
  __syncthreads();

  f4 n0, n1, nh;
#pragma unroll
  for (int b = 0; b < B; ++b) {
    if (b + 1 < B) {                        // issue batch b+1 loads early
      const float* xn = xb + bstride;
      n0 = *reinterpret_cast<const f4*>(xn + (size_t)r0 * W);
      n1 = *reinterpret_cast<const f4*>(xn + (size_t)r1 * W);
      if (has_halo)
        nh = *reinterpret_cast<const f4*>(xn + (size_t)halo_row * W);
      xb = xn;
    }

    // Outer vertical neighbors from LDS (written by adjacent threads).
    const float* s = &xs[b & 1][0][0];
    const f4 up = *reinterpret_cast<const f4*>(s + (2 * tr + 0) * W + w);
    const f4 dn = *reinterpret_cast<const f4*>(s + (2 * tr + 3) * W + w);

    float xvU[6], xv0[6], xv1[6], xvD[6];
    make_xv(xvU, up);
    make_xv(xv0, c0);
    make_xv(xv1, c1);
    make_xv(xvD, dn);

    float accP[4] = {0.f, 0.f, 0.f, 0.f};
    float accQ[4] = {0.f, 0.f, 0.f, 0.f};
    acc_row(accP, wtP, 0, xvU);             // row r0: (r0-1, r0, r0+1)
    acc_row(accP, wtP, 1, xv0);
    acc_row(accP, wtP, 2, xv1);
    acc_row(accQ, wtQ, 0, xv0);             // row r1: (r0, r1, r1+1)
    acc_row(accQ, wtQ, 1, xv1);
    acc_row(accQ, wtQ, 2, xvD);

    f4 oP, oQ;
    oP.x = accP[0]; oP.y = accP[1]; oP.z = accP[2]; oP.w = accP[3];
    oQ.x = accQ[0]; oQ.y = accQ[1]; oQ.z = accQ[2]; oQ.w = accQ[3];
    __builtin_nontemporal_store(oP, reinterpret_cast<f4*>(ob0));
    __builtin_nontemporal_store(oQ, reinterpret_cast<f4*>(ob1));
    ob0 += bstride;
    ob1 += bstride;

    if (b + 1 < B) {                        // stage batch b+1 into buf^1
      float* d = &xs[(b + 1) & 1][0][0];
      *reinterpret_cast<f4*>(d + (2 * tr + 1) * W + w) = n0;
      *reinterpret_cast<f4*>(d + (2 * tr + 2) * W + w) = n1;
      if (has_halo) *reinterpret_cast<f4*>(d + halo_slot * W + w) = nh;
      __syncthreads();
      c0 = n0;
      c1 = n1;
    }
  }
}

extern "C" void kernel_launch(void* const* d_in, const int* in_sizes, int n_in,
                              void* d_out, int out_size, void* d_ws, size_t ws_size,
                              hipStream_t stream) {
  const float* x  = (const float*)d_in[0];
  const float* wm = (const float*)d_in[1];
  float* out = (float*)d_out;

  const int blocks = C * (H / ROWS);  // 768
  tvconv_kernel<<<blocks, 256, 0, stream>>>(x, wm, out);
}